// Round 17
// baseline (123.222 us; speedup 1.0000x reference)
//
#include <hip/hip_runtime.h>
#include <hip/hip_bf16.h>

// MHA forward: B=4, S=1024, D=1024, H=16, DK=64.
// v17: R16 base (gemm_proj 512-thread, 42.9us). attn_v9: 1-deep PV pipeline —
// V(kc) pre-loaded to regs, PV(kc-1) issued right after QK^T(kc) (independent
// MFMA fills the dependency shadow), softmax after. Single sP (DS in-order
// guarantees read-before-write). LDS/occupancy unchanged.

typedef __bf16 bf16x8 __attribute__((ext_vector_type(8)));
typedef float f32x4 __attribute__((ext_vector_type(4)));
typedef unsigned short us8 __attribute__((ext_vector_type(8)));
typedef unsigned short us4 __attribute__((ext_vector_type(4)));

#define MFMA(a, b, c) __builtin_amdgcn_mfma_f32_16x16x32_bf16(a, b, c, 0, 0, 0)
#define EXP2(x) __builtin_amdgcn_exp2f(x)

__device__ __forceinline__ unsigned short f2b(float f) {
  return __builtin_bit_cast(unsigned short, __float2bfloat16(f));
}
__device__ __forceinline__ float b2f(unsigned short u) {
  return __builtin_bit_cast(float, (unsigned)u << 16);
}
__device__ __forceinline__ unsigned cvtpk(float lo, float hi) {
  unsigned r;
  asm("v_cvt_pk_bf16_f32 %0, %1, %2" : "=v"(r) : "v"(lo), "v"(hi));
  return r;
}
__device__ __forceinline__ bf16x8 ldbf8(const unsigned short* p) {
  return __builtin_bit_cast(bf16x8, *reinterpret_cast<const us8*>(p));
}
__device__ __forceinline__ us8 cvt8(float4 a, float4 b) {
  us8 o;
  o[0] = f2b(a.x); o[1] = f2b(a.y); o[2] = f2b(a.z); o[3] = f2b(a.w);
  o[4] = f2b(b.x); o[5] = f2b(b.y); o[6] = f2b(b.z); o[7] = f2b(b.w);
  return o;
}
__device__ __forceinline__ void glds16(const void* g, void* l) {
  __builtin_amdgcn_global_load_lds(
      (const __attribute__((address_space(1))) unsigned int*)g,
      (__attribute__((address_space(3))) unsigned int*)l, 16, 0, 0);
}

// prep: bid [0,1536): wq/wk/wv f32->bf16 -> Wb (3 x 1M elems, row-major).
//       bid [1536,3584): query -> Abfq; [3584,5632): key -> Abfk;
//       bid [5632,7680): value -> Abfv (launched only when ws is big enough).
__global__ __launch_bounds__(256)
void prep(const float* __restrict__ query, const float* __restrict__ key,
          const float* __restrict__ value, const float* __restrict__ wq,
          const float* __restrict__ wk, const float* __restrict__ wv,
          unsigned short* __restrict__ Abfq, unsigned short* __restrict__ Abfk,
          unsigned short* __restrict__ Abfv, unsigned short* __restrict__ Wb) {
  const int bid = blockIdx.x, tid = threadIdx.x;
  const float* src;
  unsigned short* dst;
  size_t off;
  if (bid < 1536) {
    const int widx = bid >> 9;
    src = (widx == 0) ? wq : (widx == 1) ? wk : wv;
    dst = Wb + (size_t)widx * 1048576;
    off = (size_t)(bid & 511) * 2048 + tid * 8;
  } else if (bid < 3584) {
    src = query; dst = Abfq; off = (size_t)(bid - 1536) * 2048 + tid * 8;
  } else if (bid < 5632) {
    src = key; dst = Abfk; off = (size_t)(bid - 3584) * 2048 + tid * 8;
  } else {
    src = value; dst = Abfv; off = (size_t)(bid - 5632) * 2048 + tid * 8;
  }
  const float4* p = reinterpret_cast<const float4*>(src + off);
  *reinterpret_cast<us8*>(dst + off) = cvt8(p[0], p[1]);
}

// mask[b][q][k] -> Mf in swapped QK^T C-frag order (C[k][q], q=lane&15).
// Fixed-offset softmax: unmasked = bf16(-24), masked = bf16(-1.44e9) = 0xCEAC.
__global__ __launch_bounds__(256)
void maskcvt(const int* __restrict__ mask, unsigned short* __restrict__ Mf) {
  const int idx = blockIdx.x * 256 + threadIdx.x;
  const int wl = idx & 63, tile = idx >> 6;
  const int kt = tile & 63, qt = (tile >> 6) & 63, b = tile >> 12;
  const int lr = wl & 15, lg = wl >> 4;
  const int4 mv = *reinterpret_cast<const int4*>(
      mask + (size_t)(b * 1024 + qt * 16 + lr) * 1024 + kt * 16 + lg * 4);
  us4 o;
  o[0] = mv.x ? 0xCEACu : 0xC1C0u;
  o[1] = mv.y ? 0xCEACu : 0xC1C0u;
  o[2] = mv.z ? 0xCEACu : 0xC1C0u;
  o[3] = mv.w ? 0xCEACu : 0xC1C0u;
  *reinterpret_cast<us4*>(Mf + (size_t)idx * 4) = o;
}

// single f32->bf16 1M convert (wo, after attn frees Vf slot)
__global__ __launch_bounds__(256)
void cvt_w(const float* __restrict__ src, unsigned short* __restrict__ dst) {
  const size_t off = (size_t)blockIdx.x * 2048 + threadIdx.x * 8;
  const float4* p = reinterpret_cast<const float4*>(src + off);
  *reinterpret_cast<us8*>(dst + off) = cvt8(p[0], p[1]);
}

// Projection GEMM v16 (unchanged): BM=128, BN=128, BK=32; 512 threads = 8 waves
// (2x4), wave tile 64x32; dbuf 32KB LDS; T14 issue-early glds staging.
__global__ __launch_bounds__(512, 6)
void gemm_proj(const unsigned short* __restrict__ Aq,
               const unsigned short* __restrict__ Ak,
               const unsigned short* __restrict__ Av_bf,
               const float* __restrict__ Av_f32,
               const unsigned short* __restrict__ Wb,
               const float* __restrict__ bq, const float* __restrict__ bk,
               const float* __restrict__ bv, unsigned short* __restrict__ Qb,
               unsigned short* __restrict__ Kf, unsigned short* __restrict__ Vf,
               float qscale) {
  constexpr int K = 1024, N = 1024;
  __shared__ __align__(16) unsigned short As[2][128 * 32];
  __shared__ __align__(16) unsigned short Bs[2][128 * 32];
  const int lid = blockIdx.x + (blockIdx.y << 5) + (blockIdx.z << 8);
  const int xcd = lid & 7, slot = lid >> 3;
  const int chunk = ((slot >> 3) << 3) + xcd;
  const int z = chunk >> 5;
  const int bm = (chunk & 31) * 128;
  const int bn = (slot & 7) * 128;

  const unsigned short* Abf = (z == 0) ? Aq : (z == 1) ? Ak : Av_bf;
  const bool f32path = (z == 2) && (Av_bf == nullptr);
  const unsigned short* Bw = Wb + (size_t)z * 1048576;
  const float* bias = (z == 0) ? bq : (z == 1) ? bk : bv;
  const int t = threadIdx.x;
  const int w = t >> 6, lane = t & 63, lr = lane & 15, lg = lane >> 4;
  const int wr = w >> 2, wc = w & 3;

#define SWZ(row) ((((row) ^ ((row) >> 2)) & 3) << 4)

  f32x4 acc[4][2];
#pragma unroll
  for (int m = 0; m < 4; ++m)
#pragma unroll
    for (int n = 0; n < 2; ++n) acc[m][n] = f32x4{0.f, 0.f, 0.f, 0.f};

  auto stageA = [&](int k0, int buf) {
    const int row = t >> 2, cb = (t & 3) * 16;
    const char* g = (const char*)Abf + ((size_t)(bm + row) * 1024 + k0) * 2 +
                    (cb ^ SWZ(row));
    char* l = (char*)&As[buf][0] + (w * 64) * 16;
    glds16(g, l);
  };
  auto stageB = [&](int k0, int buf) {
    const int row = t >> 2, cb = (t & 3) * 16;
    const char* g = (const char*)Bw + ((size_t)(bn + row) * 1024 + k0) * 2 +
                    (cb ^ SWZ(row));
    char* l = (char*)&Bs[buf][0] + (w * 64) * 16;
    glds16(g, l);
  };
#define STA8(buf, v)                                                           \
  {                                                                            \
    const int row_ = t >> 2, cb_ = (t & 3) * 16;                               \
    *reinterpret_cast<us8*>((char*)&As[buf][0] + row_ * 64 +                   \
                            (cb_ ^ SWZ(row_))) = (v);                          \
  }

  if (f32path) {
    const int row = t >> 2, col = (t & 3) * 8;
    const float4* p =
        reinterpret_cast<const float4*>(Av_f32 + (size_t)(bm + row) * K + col);
    STA8(0, cvt8(p[0], p[1]));
  } else {
    stageA(0, 0);
  }
  stageB(0, 0);
  __syncthreads();

  for (int c = 0; c < 32; ++c) {
    const int buf = c & 1;
    float4 fa[2];
    if (c < 31) {
      const int k1 = (c + 1) * 32;
      if (f32path) {
        const int row = t >> 2, col = (t & 3) * 8;
        const float4* p = reinterpret_cast<const float4*>(
            Av_f32 + (size_t)(bm + row) * K + k1 + col);
        fa[0] = p[0];
        fa[1] = p[1];
      } else {
        stageA(k1, buf ^ 1);
      }
      stageB(k1, buf ^ 1);
    }
    {
      bf16x8 af[4], bfr[2];
#pragma unroll
      for (int m = 0; m < 4; ++m) {
        const int row = wr * 64 + m * 16 + lr;
        af[m] = ldbf8((const unsigned short*)((char*)&As[buf][0] + row * 64 +
                                              ((lg * 16) ^ SWZ(row))));
      }
#pragma unroll
      for (int n = 0; n < 2; ++n) {
        const int row = wc * 32 + n * 16 + lr;
        bfr[n] = ldbf8((const unsigned short*)((char*)&Bs[buf][0] + row * 64 +
                                               ((lg * 16) ^ SWZ(row))));
      }
#pragma unroll
      for (int m = 0; m < 4; ++m)
#pragma unroll
        for (int n = 0; n < 2; ++n) acc[m][n] = MFMA(af[m], bfr[n], acc[m][n]);
    }
    if (c < 31 && f32path) {
      STA8(buf ^ 1, cvt8(fa[0], fa[1]));
    }
    __syncthreads();
  }
#undef STA8
#undef SWZ

#pragma unroll
  for (int m = 0; m < 4; ++m) {
    const int mr = bm + wr * 64 + m * 16 + lg * 4;
#pragma unroll
    for (int nt = 0; nt < 2; ++nt) {
      const int n = bn + wc * 32 + nt * 16 + lr;
      const float bb = bias[n];
      if (z == 0) {
#pragma unroll
        for (int r = 0; r < 4; ++r)
          Qb[(size_t)(mr + r) * N + n] = f2b((acc[m][nt][r] + bb) * qscale);
      } else if (z == 1) {
        // Kf: K[bh][s][d] -> bh*65536 + (d>>5)*32768 + (s>>4)*512
        //     + ((s&15)|(((d>>3)&3)<<4))*8 + (d&7)
        const int b2 = mr >> 10, s0 = mr & 1023, hh = n >> 6, dd = n & 63;
        const size_t base = (size_t)(b2 * 16 + hh) * 65536 + (size_t)(dd >> 5) * 32768 +
                            (size_t)(s0 >> 4) * 512 +
                            (size_t)((s0 & 15) | (((dd >> 3) & 3) << 4)) * 8 + (dd & 7);
#pragma unroll
        for (int r = 0; r < 4; ++r) Kf[base + r * 8] = f2b(acc[m][nt][r] + bb);
      } else {
        // Vf: V[bh][s][d] -> bh*65536 + (s>>5)*2048 + (d>>4)*512
        //     + ((d&15)|(((s>>3)&3)<<4))*8 + (s&7)
        const int b2 = mr >> 10, s0 = mr & 1023, hh = n >> 6, dd = n & 63;
        const size_t base = (size_t)(b2 * 16 + hh) * 65536 + (size_t)(s0 >> 5) * 2048 +
                            (size_t)(dd >> 4) * 512 +
                            (size_t)((dd & 15) | (((s0 >> 3) & 3) << 4)) * 8 + (s0 & 7);
        us4 pk;
#pragma unroll
        for (int r = 0; r < 4; ++r) pk[r] = f2b(acc[m][nt][r] + bb);
        *reinterpret_cast<us4*>(&Vf[base]) = pk;
      }
    }
  }
}

// Output projection: BM=128, BN=64, all-glds dbuf (unchanged).
__global__ __launch_bounds__(256)
void gemm_out(const unsigned short* __restrict__ A, const unsigned short* __restrict__ Bw,
              const float* __restrict__ bias, float* __restrict__ Out) {
  constexpr int K = 1024, N = 1024;
  __shared__ __align__(16) unsigned short As[2][128 * 64];
  __shared__ __align__(16) unsigned short Bs[2][64 * 64];
  const int lid = blockIdx.x + (blockIdx.y << 5);
  const int xcd = lid & 7, slot = lid >> 3;
  const int chunk = ((slot >> 5) << 3) + xcd;
  const int pos = slot & 31;
  const int bm = ((chunk << 1) + (pos >> 4)) * 128;
  const int bn = (pos & 15) * 64;
  const int t = threadIdx.x;
  const int w = t >> 6, lane = t & 63, lr = lane & 15, lg = lane >> 4;
  const int wr = w >> 1, wc = w & 1;
  const int swzc = (lr & 7) << 4;

  f32x4 acc[4][2];
#pragma unroll
  for (int m = 0; m < 4; ++m)
#pragma unroll
    for (int n = 0; n < 2; ++n) acc[m][n] = f32x4{0.f, 0.f, 0.f, 0.f};

  auto stageA = [&](int k0, int buf) {
#pragma unroll
    for (int it = 0; it < 4; ++it) {
      const int s = it * 256 + t, row = s >> 3, cb = (s & 7) * 16;
      const char* g = (const char*)A + ((size_t)(bm + row) * 1024 + k0) * 2 +
                      (cb ^ ((row & 7) << 4));
      char* l = (char*)&As[buf][0] + (it * 256 + w * 64) * 16;
      glds16(g, l);
    }
  };
  auto stageB = [&](int k0, int buf) {
#pragma unroll
    for (int it = 0; it < 2; ++it) {
      const int s = it * 256 + t, row = s >> 3, cb = (s & 7) * 16;
      const char* g = (const char*)Bw + ((size_t)(bn + row) * 1024 + k0) * 2 +
                      (cb ^ ((row & 7) << 4));
      char* l = (char*)&Bs[buf][0] + (it * 256 + w * 64) * 16;
      glds16(g, l);
    }
  };

  stageA(0, 0);
  stageB(0, 0);
  __syncthreads();

  for (int c = 0; c < 16; ++c) {
    const int buf = c & 1;
    if (c < 15) {
      const int k1 = (c + 1) * 64;
      stageA(k1, buf ^ 1);
      stageB(k1, buf ^ 1);
    }
#pragma unroll
    for (int h2 = 0; h2 < 2; ++h2) {
      bf16x8 af[4], bfr[2];
#pragma unroll
      for (int m = 0; m < 4; ++m) {
        const int row = wr * 64 + m * 16 + lr;
        af[m] = ldbf8((const unsigned short*)((char*)&As[buf][0] + row * 128 +
                                              ((h2 * 64 + lg * 16) ^ swzc)));
      }
#pragma unroll
      for (int n = 0; n < 2; ++n) {
        const int row = wc * 32 + n * 16 + lr;
        bfr[n] = ldbf8((const unsigned short*)((char*)&Bs[buf][0] + row * 128 +
                                               ((h2 * 64 + lg * 16) ^ swzc)));
      }
#pragma unroll
      for (int m = 0; m < 4; ++m)
#pragma unroll
        for (int n = 0; n < 2; ++n) acc[m][n] = MFMA(af[m], bfr[n], acc[m][n]);
    }
    __syncthreads();
  }

#pragma unroll
  for (int m = 0; m < 4; ++m) {
    const int mr = bm + wr * 64 + m * 16 + lg * 4;
#pragma unroll
    for (int nt = 0; nt < 2; ++nt) {
      const int n = bn + wc * 32 + nt * 16 + lr;
      const float bb = bias[n];
#pragma unroll
      for (int r = 0; r < 4; ++r) Out[(size_t)(mr + r) * N + n] = acc[m][nt][r] + bb;
    }
  }
}

// Flash attention v9: 1-deep PV pipeline. V(kc) pre-loaded to regs; PV(kc-1)
// issued right after QK^T(kc); softmax after. Single sP (DS in-order per wave
// keeps the PV reads ahead of the softmax writes). WG-shared K/V glds staging,
// fixed-offset softmax via Mf, cvt_pk P-pack, setprio. Swapped QK^T.
__global__ __launch_bounds__(256)
void attn_v9(const unsigned short* __restrict__ Qb,
             const unsigned short* __restrict__ Kf,
             const unsigned short* __restrict__ Vf,
             const unsigned short* __restrict__ Mf,
             unsigned short* __restrict__ ctx) {
  __shared__ __align__(16) unsigned short S[2][8192];
  __shared__ __align__(16) unsigned short sP[4][16 * 64];
  const int lid = blockIdx.x + (blockIdx.y << 6);
  const int xcd = lid & 7, slot = lid >> 3;
  const int bh = ((slot >> 4) << 3) + xcd;
  const int qb = slot & 15;
  const int b = bh >> 4, h = bh & 15;
  const int t = threadIdx.x, w = t >> 6, wl = t & 63, lr = wl & 15, lg = wl >> 4;
  const int q0 = qb * 64 + w * 16;
  const int swz = (lr & 7) << 4;

  const unsigned short* qp = Qb + (size_t)(b * 1024 + q0 + lr) * 1024 + h * 64 + lg * 8;
  const bf16x8 bq0 = ldbf8(qp);
  const bf16x8 bq1 = ldbf8(qp + 32);

  const unsigned short* KfB = Kf + (size_t)bh * 65536;
  const unsigned short* VfB = Vf + (size_t)bh * 65536;
  const unsigned short* mfp = Mf + (size_t)((b * 64 + qb * 4 + w) * 64) * 256 + wl * 4;

  f32x4 O[4];
  float l_ = 0.f;
#pragma unroll
  for (int dt = 0; dt < 4; ++dt) O[dt] = f32x4{0.f, 0.f, 0.f, 0.f};
  unsigned short* sp = &sP[w][0];
  bf16x8 bvp[2][4];  // V regs of the previous chunk (PV operand)

  auto stage = [&](int kc, int buf) {
    const unsigned short* srcs[4] = {KfB + kc * 2048, KfB + 32768 + kc * 2048,
                                     VfB + kc * 4096, VfB + kc * 4096 + 2048};
#pragma unroll
    for (int r = 0; r < 4; ++r) {
      const char* g = (const char*)(srcs[r] + (size_t)t * 8);
      char* l = (char*)&S[buf][r * 2048 + w * 512];
      glds16(g, l);
    }
  };

  stage(0, 0);
  __syncthreads();

  for (int kc = 0; kc < 16; ++kc) {
    const int buf = kc & 1;
    if (kc < 15) stage(kc + 1, buf ^ 1);

    us4 mk[4];
#pragma unroll
    for (int t4 = 0; t4 < 4; ++t4)
      mk[t4] = *reinterpret_cast<const us4*>(mfp + (size_t)(kc * 4 + t4) * 256);

    bf16x8 ak[4][2];
#pragma unroll
    for (int t4 = 0; t4 < 4; ++t4) {
      ak[t4][0] = ldbf8(&S[buf][t4 * 512 + wl * 8]);
      ak[t4][1] = ldbf8(&S[buf][2048 + t4 * 512 + wl * 8]);
    }

    // QK^T(kc) — MFMA cluster
    f32x4 sc[4];
    __builtin_amdgcn_s_setprio(1);
#pragma unroll
    for (int t4 = 0; t4 < 4; ++t4) {
      f32x4 a;
#pragma unroll
      for (int r = 0; r < 4; ++r) a[r] = b2f(mk[t4][r]);
      a = MFMA(ak[t4][0], bq0, a);
      a = MFMA(ak[t4][1], bq1, a);
      sc[t4] = a;
    }
    // PV(kc-1) — independent MFMA, fills QK^T's dependency shadow.
    // sP reads are issued BEFORE softmax(kc)'s writes (DS in-order per wave).
    if (kc > 0) {
#pragma unroll
      for (int ks = 0; ks < 2; ++ks) {
        bf16x8 ap = ldbf8(
            (const unsigned short*)((char*)sp + lr * 128 + ((ks * 64 + lg * 16) ^ swz)));
#pragma unroll
        for (int dt = 0; dt < 4; ++dt) O[dt] = MFMA(ap, bvp[ks][dt], O[dt]);
      }
    }
    __builtin_amdgcn_s_setprio(0);

    // softmax(kc) -> sP
    float ps = 0.f;
#pragma unroll
    for (int t4 = 0; t4 < 4; ++t4) {
      const float e0 = EXP2(sc[t4][0]), e1 = EXP2(sc[t4][1]);
      const float e2 = EXP2(sc[t4][2]), e3 = EXP2(sc[t4][3]);
      ps += (e0 + e1) + (e2 + e3);
      uint2 pw;
      pw.x = cvtpk(e0, e1);
      pw.y = cvtpk(e2, e3);
      *reinterpret_cast<uint2*>((char*)sp + lr * 128 + ((t4 * 32 + lg * 8) ^ swz)) = pw;
    }
    ps += __shfl_xor(ps, 16);
    ps += __shfl_xor(ps, 32);
    l_ += ps;

    // V(kc) -> regs for next iteration's PV (read before S[buf] is recycled)
#pragma unroll
    for (int ks = 0; ks < 2; ++ks)
#pragma unroll
      for (int dt = 0; dt < 4; ++dt)
        bvp[ks][dt] = ldbf8(&S[buf][4096 + ks * 2048 + dt * 512 + wl * 8]);

    __syncthreads();
  }

  // epilogue: PV(15)
#pragma unroll
  for (int ks = 0; ks < 2; ++ks) {
    bf16x8 ap =
        ldbf8((const unsigned short*)((char*)sp + lr * 128 + ((ks * 64 + lg * 16) ^ swz)));
#pragma unroll
    for (int dt = 0; dt < 4; ++dt) O[dt] = MFMA(ap, bvp[ks][dt], O[dt]);
  }

  float linv[4];
#pragma unroll
  for (int r = 0; r < 4; ++r) linv[r] = 1.0f / __shfl(l_, lg * 4 + r);
#pragma unroll
  for (int dt = 0; dt < 4; ++dt)
#pragma unroll
    for (int r = 0; r < 4; ++r)
      ctx[(size_t)(b * 1024 + q0 + lg * 4 + r) * 1024 + h * 64 + dt * 16 + lr] =
          f2b(O[dt][r] * linv[r]);
}

extern "C" void kernel_launch(void* const* d_in, const int* in_sizes, int n_in,
                              void* d_out, int out_size, void* d_ws, size_t ws_size,
                              hipStream_t stream) {
  const float* query = (const float*)d_in[0];
  const float* key   = (const float*)d_in[1];
  const float* value = (const float*)d_in[2];
  const int*   mask  = (const int*)d_in[3];
  const float* wq = (const float*)d_in[4];
  const float* bq = (const float*)d_in[5];
  const float* wk = (const float*)d_in[6];
  const float* bk = (const float*)d_in[7];
  const float* wv = (const float*)d_in[8];
  const float* bv = (const float*)d_in[9];
  const float* wo = (const float*)d_in[10];
  const float* bo = (const float*)d_in[11];
  float* out = (float*)d_out;

  // ws [0..32MB): Qb, Kf, Vf, ctx (bf16, 8MB each). ctx slot doubles as Abfk
  // during the projection. d_out: Abfq [0..8M) then Mf overlays it; Wb [8..14M).
  // Abfv at ws+32MB only if ws_size >= 40MB. wo(bf16) -> Vf slot after attn.
  const size_t SZ = (size_t)4096 * 1024;
  unsigned short* Qb   = (unsigned short*)d_ws;
  unsigned short* Kf   = Qb + SZ;
  unsigned short* Vf   = Kf + SZ;
  unsigned short* ctx  = Vf + SZ;
  unsigned short* Abfq = (unsigned short*)d_out;
  unsigned short* Wb   = Abfq + SZ;
  unsigned short* Mf   = (unsigned short*)d_out;  // after projection
  unsigned short* Abfk = ctx;                     // before attn
  const bool big = ws_size >= (size_t)40 * 1024 * 1024;
  unsigned short* Abfv = big ? (ctx + SZ) : nullptr;  // ws+32MB
  unsigned short* Wob  = Vf;                          // after attn

  const float qscale = 0.125f * 1.4426950408889634f;  // 1/sqrt(64) * log2(e)
  dim3 blk(256);
  prep<<<big ? 7680 : 5632, blk, 0, stream>>>(query, key, value, wq, wk, wv,
                                              Abfq, Abfk, Abfv, Wb);
  gemm_proj<<<dim3(32, 8, 3), dim3(512), 0, stream>>>(Abfq, Abfk, Abfv, value, Wb,
                                                      bq, bk, bv, Qb, Kf, Vf, qscale);
  maskcvt<<<4096, blk, 0, stream>>>(mask, Mf);
  attn_v9<<<dim3(64, 16), blk, 0, stream>>>(Qb, Kf, Vf, Mf, ctx);
  cvt_w<<<512, blk, 0, stream>>>(wo, Wob);
  gemm_out<<<dim3(32, 16), blk, 0, stream>>>(ctx, Wob, bo, out);
}

// Round 18
// 116.487 us; speedup vs baseline: 1.0578x; 1.0578x over previous
//
#include <hip/hip_runtime.h>
#include <hip/hip_bf16.h>

// MHA forward: B=4, S=1024, D=1024, H=16, DK=64.
// v18: R16 base. gemm_proj LDS layout reworked to row-pair-interleaved 128B
// lines (conflict-free b128 reads at BK=32; R16's 2-bit swizzle was 8-way).
// attn_v7 restored (v9 pipeline regressed). prep/maskcvt/cvt_w/gemm_out = R16.

typedef __bf16 bf16x8 __attribute__((ext_vector_type(8)));
typedef float f32x4 __attribute__((ext_vector_type(4)));
typedef unsigned short us8 __attribute__((ext_vector_type(8)));
typedef unsigned short us4 __attribute__((ext_vector_type(4)));

#define MFMA(a, b, c) __builtin_amdgcn_mfma_f32_16x16x32_bf16(a, b, c, 0, 0, 0)
#define EXP2(x) __builtin_amdgcn_exp2f(x)

__device__ __forceinline__ unsigned short f2b(float f) {
  return __builtin_bit_cast(unsigned short, __float2bfloat16(f));
}
__device__ __forceinline__ float b2f(unsigned short u) {
  return __builtin_bit_cast(float, (unsigned)u << 16);
}
__device__ __forceinline__ unsigned cvtpk(float lo, float hi) {
  unsigned r;
  asm("v_cvt_pk_bf16_f32 %0, %1, %2" : "=v"(r) : "v"(lo), "v"(hi));
  return r;
}
__device__ __forceinline__ bf16x8 ldbf8(const unsigned short* p) {
  return __builtin_bit_cast(bf16x8, *reinterpret_cast<const us8*>(p));
}
__device__ __forceinline__ us8 cvt8(float4 a, float4 b) {
  us8 o;
  o[0] = f2b(a.x); o[1] = f2b(a.y); o[2] = f2b(a.z); o[3] = f2b(a.w);
  o[4] = f2b(b.x); o[5] = f2b(b.y); o[6] = f2b(b.z); o[7] = f2b(b.w);
  return o;
}
__device__ __forceinline__ void glds16(const void* g, void* l) {
  __builtin_amdgcn_global_load_lds(
      (const __attribute__((address_space(1))) unsigned int*)g,
      (__attribute__((address_space(3))) unsigned int*)l, 16, 0, 0);
}

// prep: bid [0,1536): wq/wk/wv f32->bf16 -> Wb (3 x 1M elems, row-major).
//       bid [1536,3584): query -> Abfq; [3584,5632): key -> Abfk;
//       bid [5632,7680): value -> Abfv (launched only when ws is big enough).
__global__ __launch_bounds__(256)
void prep(const float* __restrict__ query, const float* __restrict__ key,
          const float* __restrict__ value, const float* __restrict__ wq,
          const float* __restrict__ wk, const float* __restrict__ wv,
          unsigned short* __restrict__ Abfq, unsigned short* __restrict__ Abfk,
          unsigned short* __restrict__ Abfv, unsigned short* __restrict__ Wb) {
  const int bid = blockIdx.x, tid = threadIdx.x;
  const float* src;
  unsigned short* dst;
  size_t off;
  if (bid < 1536) {
    const int widx = bid >> 9;
    src = (widx == 0) ? wq : (widx == 1) ? wk : wv;
    dst = Wb + (size_t)widx * 1048576;
    off = (size_t)(bid & 511) * 2048 + tid * 8;
  } else if (bid < 3584) {
    src = query; dst = Abfq; off = (size_t)(bid - 1536) * 2048 + tid * 8;
  } else if (bid < 5632) {
    src = key; dst = Abfk; off = (size_t)(bid - 3584) * 2048 + tid * 8;
  } else {
    src = value; dst = Abfv; off = (size_t)(bid - 5632) * 2048 + tid * 8;
  }
  const float4* p = reinterpret_cast<const float4*>(src + off);
  *reinterpret_cast<us8*>(dst + off) = cvt8(p[0], p[1]);
}

// mask[b][q][k] -> Mf in swapped QK^T C-frag order (C[k][q], q=lane&15).
// Fixed-offset softmax: unmasked = bf16(-24), masked = bf16(-1.44e9) = 0xCEAC.
__global__ __launch_bounds__(256)
void maskcvt(const int* __restrict__ mask, unsigned short* __restrict__ Mf) {
  const int idx = blockIdx.x * 256 + threadIdx.x;
  const int wl = idx & 63, tile = idx >> 6;
  const int kt = tile & 63, qt = (tile >> 6) & 63, b = tile >> 12;
  const int lr = wl & 15, lg = wl >> 4;
  const int4 mv = *reinterpret_cast<const int4*>(
      mask + (size_t)(b * 1024 + qt * 16 + lr) * 1024 + kt * 16 + lg * 4);
  us4 o;
  o[0] = mv.x ? 0xCEACu : 0xC1C0u;
  o[1] = mv.y ? 0xCEACu : 0xC1C0u;
  o[2] = mv.z ? 0xCEACu : 0xC1C0u;
  o[3] = mv.w ? 0xCEACu : 0xC1C0u;
  *reinterpret_cast<us4*>(Mf + (size_t)idx * 4) = o;
}

// single f32->bf16 1M convert (wo, after attn frees Vf slot)
__global__ __launch_bounds__(256)
void cvt_w(const float* __restrict__ src, unsigned short* __restrict__ dst) {
  const size_t off = (size_t)blockIdx.x * 2048 + threadIdx.x * 8;
  const float4* p = reinterpret_cast<const float4*>(src + off);
  *reinterpret_cast<us8*>(dst + off) = cvt8(p[0], p[1]);
}

// Projection GEMM v18: BM=128, BN=128, BK=32; 512 threads = 8 waves (2x4),
// wave tile 64x32; dbuf 32KB LDS; glds staging. LDS layout: row-pairs in
// 128B lines, slot8 = (lg | ((row&1)<<2)) ^ ((row>>1)&7) -> conflict-free
// b128 reads (32 banks covered per line). Staging inverts the bijection on
// the global source address (linear LDS dest).
__global__ __launch_bounds__(512, 6)
void gemm_proj(const unsigned short* __restrict__ Aq,
               const unsigned short* __restrict__ Ak,
               const unsigned short* __restrict__ Av_bf,
               const float* __restrict__ Av_f32,
               const unsigned short* __restrict__ Wb,
               const float* __restrict__ bq, const float* __restrict__ bk,
               const float* __restrict__ bv, unsigned short* __restrict__ Qb,
               unsigned short* __restrict__ Kf, unsigned short* __restrict__ Vf,
               float qscale) {
  constexpr int K = 1024, N = 1024;
  __shared__ __align__(16) unsigned short As[2][128 * 32];  // 8KB each
  __shared__ __align__(16) unsigned short Bs[2][128 * 32];
  const int lid = blockIdx.x + (blockIdx.y << 5) + (blockIdx.z << 8);
  const int xcd = lid & 7, slot = lid >> 3;
  const int chunk = ((slot >> 3) << 3) + xcd;
  const int z = chunk >> 5;
  const int bm = (chunk & 31) * 128;
  const int bn = (slot & 7) * 128;

  const unsigned short* Abf = (z == 0) ? Aq : (z == 1) ? Ak : Av_bf;
  const bool f32path = (z == 2) && (Av_bf == nullptr);
  const unsigned short* Bw = Wb + (size_t)z * 1048576;
  const float* bias = (z == 0) ? bq : (z == 1) ? bk : bv;
  const int t = threadIdx.x;
  const int w = t >> 6, lane = t & 63, lr = lane & 15, lg = lane >> 4;
  const int wr = w >> 2, wc = w & 3;  // 2x4 wave grid

  // Staging decode: LDS byte addr = t*16 (linear). line = t>>3, s8 = t&7;
  // u = s8 ^ (line&7); row = line*2 + (u>>2); col16 = u&3.
  const int sline = t >> 3;
  const int su = (t & 7) ^ (sline & 7);
  const int srow = sline * 2 + (su >> 2);
  const int scol = (su & 3) * 8;  // element col (8 bf16 = 16B)

  f32x4 acc[4][2];
#pragma unroll
  for (int m = 0; m < 4; ++m)
#pragma unroll
    for (int n = 0; n < 2; ++n) acc[m][n] = f32x4{0.f, 0.f, 0.f, 0.f};

  auto stageA = [&](int k0, int buf) {
    const char* g = (const char*)(Abf + (size_t)(bm + srow) * 1024 + k0 + scol);
    char* l = (char*)&As[buf][0] + (w * 64) * 16;  // wave-uniform base
    glds16(g, l);
  };
  auto stageB = [&](int k0, int buf) {
    const char* g = (const char*)(Bw + (size_t)(bn + srow) * 1024 + k0 + scol);
    char* l = (char*)&Bs[buf][0] + (w * 64) * 16;
    glds16(g, l);
  };
#define STA8(buf, v)                                                           \
  { *reinterpret_cast<us8*>((char*)&As[buf][0] + t * 16) = (v); }

  // Fragment read address for row, 16B block lg (byte offset in tile)
#define RDOFF(row) (((row) >> 1) * 128 +                                       \
                    (((lg | (((row) & 1) << 2)) ^ (((row) >> 1) & 7)) * 16))

  // prologue: stage c=0 into buf 0
  if (f32path) {
    const float4* p =
        reinterpret_cast<const float4*>(Av_f32 + (size_t)(bm + srow) * K + scol);
    STA8(0, cvt8(p[0], p[1]));
  } else {
    stageA(0, 0);
  }
  stageB(0, 0);
  __syncthreads();

  for (int c = 0; c < 32; ++c) {
    const int buf = c & 1;
    float4 fa[2];
    if (c < 31) {  // T14: issue next-tile staging before compute
      const int k1 = (c + 1) * 32;
      if (f32path) {
        const float4* p = reinterpret_cast<const float4*>(
            Av_f32 + (size_t)(bm + srow) * K + k1 + scol);
        fa[0] = p[0];
        fa[1] = p[1];
      } else {
        stageA(k1, buf ^ 1);
      }
      stageB(k1, buf ^ 1);
    }
    // compute current tile: 6 ds_read_b128 + 8 MFMA per wave (conflict-free)
    {
      bf16x8 af[4], bfr[2];
#pragma unroll
      for (int m = 0; m < 4; ++m) {
        const int row = wr * 64 + m * 16 + lr;
        af[m] = ldbf8((const unsigned short*)((char*)&As[buf][0] + RDOFF(row)));
      }
#pragma unroll
      for (int n = 0; n < 2; ++n) {
        const int row = wc * 32 + n * 16 + lr;
        bfr[n] = ldbf8((const unsigned short*)((char*)&Bs[buf][0] + RDOFF(row)));
      }
#pragma unroll
      for (int m = 0; m < 4; ++m)
#pragma unroll
        for (int n = 0; n < 2; ++n) acc[m][n] = MFMA(af[m], bfr[n], acc[m][n]);
    }
    if (c < 31 && f32path) {  // write-late A convert
      STA8(buf ^ 1, cvt8(fa[0], fa[1]));
    }
    __syncthreads();
  }
#undef STA8
#undef RDOFF

#pragma unroll
  for (int m = 0; m < 4; ++m) {
    const int mr = bm + wr * 64 + m * 16 + lg * 4;
#pragma unroll
    for (int nt = 0; nt < 2; ++nt) {
      const int n = bn + wc * 32 + nt * 16 + lr;
      const float bb = bias[n];
      if (z == 0) {
#pragma unroll
        for (int r = 0; r < 4; ++r)
          Qb[(size_t)(mr + r) * N + n] = f2b((acc[m][nt][r] + bb) * qscale);
      } else if (z == 1) {
        // Kf: K[bh][s][d] -> bh*65536 + (d>>5)*32768 + (s>>4)*512
        //     + ((s&15)|(((d>>3)&3)<<4))*8 + (d&7)
        const int b2 = mr >> 10, s0 = mr & 1023, hh = n >> 6, dd = n & 63;
        const size_t base = (size_t)(b2 * 16 + hh) * 65536 + (size_t)(dd >> 5) * 32768 +
                            (size_t)(s0 >> 4) * 512 +
                            (size_t)((s0 & 15) | (((dd >> 3) & 3) << 4)) * 8 + (dd & 7);
#pragma unroll
        for (int r = 0; r < 4; ++r) Kf[base + r * 8] = f2b(acc[m][nt][r] + bb);
      } else {
        // Vf: V[bh][s][d] -> bh*65536 + (s>>5)*2048 + (d>>4)*512
        //     + ((d&15)|(((s>>3)&3)<<4))*8 + (s&7)
        const int b2 = mr >> 10, s0 = mr & 1023, hh = n >> 6, dd = n & 63;
        const size_t base = (size_t)(b2 * 16 + hh) * 65536 + (size_t)(s0 >> 5) * 2048 +
                            (size_t)(dd >> 4) * 512 +
                            (size_t)((dd & 15) | (((s0 >> 3) & 3) << 4)) * 8 + (s0 & 7);
        us4 pk;
#pragma unroll
        for (int r = 0; r < 4; ++r) pk[r] = f2b(acc[m][nt][r] + bb);
        *reinterpret_cast<us4*>(&Vf[base]) = pk;
      }
    }
  }
}

// Output projection: BM=128, BN=64, all-glds dbuf (unchanged).
__global__ __launch_bounds__(256)
void gemm_out(const unsigned short* __restrict__ A, const unsigned short* __restrict__ Bw,
              const float* __restrict__ bias, float* __restrict__ Out) {
  constexpr int K = 1024, N = 1024;
  __shared__ __align__(16) unsigned short As[2][128 * 64];
  __shared__ __align__(16) unsigned short Bs[2][64 * 64];
  const int lid = blockIdx.x + (blockIdx.y << 5);
  const int xcd = lid & 7, slot = lid >> 3;
  const int chunk = ((slot >> 5) << 3) + xcd;
  const int pos = slot & 31;
  const int bm = ((chunk << 1) + (pos >> 4)) * 128;
  const int bn = (pos & 15) * 64;
  const int t = threadIdx.x;
  const int w = t >> 6, lane = t & 63, lr = lane & 15, lg = lane >> 4;
  const int wr = w >> 1, wc = w & 1;
  const int swzc = (lr & 7) << 4;

  f32x4 acc[4][2];
#pragma unroll
  for (int m = 0; m < 4; ++m)
#pragma unroll
    for (int n = 0; n < 2; ++n) acc[m][n] = f32x4{0.f, 0.f, 0.f, 0.f};

  auto stageA = [&](int k0, int buf) {
#pragma unroll
    for (int it = 0; it < 4; ++it) {
      const int s = it * 256 + t, row = s >> 3, cb = (s & 7) * 16;
      const char* g = (const char*)A + ((size_t)(bm + row) * 1024 + k0) * 2 +
                      (cb ^ ((row & 7) << 4));
      char* l = (char*)&As[buf][0] + (it * 256 + w * 64) * 16;
      glds16(g, l);
    }
  };
  auto stageB = [&](int k0, int buf) {
#pragma unroll
    for (int it = 0; it < 2; ++it) {
      const int s = it * 256 + t, row = s >> 3, cb = (s & 7) * 16;
      const char* g = (const char*)Bw + ((size_t)(bn + row) * 1024 + k0) * 2 +
                      (cb ^ ((row & 7) << 4));
      char* l = (char*)&Bs[buf][0] + (it * 256 + w * 64) * 16;
      glds16(g, l);
    }
  };

  stageA(0, 0);
  stageB(0, 0);
  __syncthreads();

  for (int c = 0; c < 16; ++c) {
    const int buf = c & 1;
    if (c < 15) {
      const int k1 = (c + 1) * 64;
      stageA(k1, buf ^ 1);
      stageB(k1, buf ^ 1);
    }
#pragma unroll
    for (int h2 = 0; h2 < 2; ++h2) {
      bf16x8 af[4], bfr[2];
#pragma unroll
      for (int m = 0; m < 4; ++m) {
        const int row = wr * 64 + m * 16 + lr;
        af[m] = ldbf8((const unsigned short*)((char*)&As[buf][0] + row * 128 +
                                              ((h2 * 64 + lg * 16) ^ swzc)));
      }
#pragma unroll
      for (int n = 0; n < 2; ++n) {
        const int row = wc * 32 + n * 16 + lr;
        bfr[n] = ldbf8((const unsigned short*)((char*)&Bs[buf][0] + row * 128 +
                                               ((h2 * 64 + lg * 16) ^ swzc)));
      }
#pragma unroll
      for (int m = 0; m < 4; ++m)
#pragma unroll
        for (int n = 0; n < 2; ++n) acc[m][n] = MFMA(af[m], bfr[n], acc[m][n]);
    }
    __syncthreads();
  }

#pragma unroll
  for (int m = 0; m < 4; ++m) {
    const int mr = bm + wr * 64 + m * 16 + lg * 4;
#pragma unroll
    for (int nt = 0; nt < 2; ++nt) {
      const int n = bn + wc * 32 + nt * 16 + lr;
      const float bb = bias[n];
#pragma unroll
      for (int r = 0; r < 4; ++r) Out[(size_t)(mr + r) * N + n] = acc[m][nt][r] + bb;
    }
  }
}

// Flash attention v7 (R12/R16, unchanged): WG-shared K/V LDS staging (glds
// dbuf), fixed-offset softmax via Mf, cvt_pk P-pack, setprio. Swapped QK^T.
__global__ __launch_bounds__(256)
void attn_v7(const unsigned short* __restrict__ Qb,
             const unsigned short* __restrict__ Kf,
             const unsigned short* __restrict__ Vf,
             const unsigned short* __restrict__ Mf,
             unsigned short* __restrict__ ctx) {
  __shared__ __align__(16) unsigned short S[2][8192];
  __shared__ __align__(16) unsigned short sP[4][16 * 64];
  const int lid = blockIdx.x + (blockIdx.y << 6);
  const int xcd = lid & 7, slot = lid >> 3;
  const int bh = ((slot >> 4) << 3) + xcd;
  const int qb = slot & 15;
  const int b = bh >> 4, h = bh & 15;
  const int t = threadIdx.x, w = t >> 6, wl = t & 63, lr = wl & 15, lg = wl >> 4;
  const int q0 = qb * 64 + w * 16;
  const int swz = (lr & 7) << 4;

  const unsigned short* qp = Qb + (size_t)(b * 1024 + q0 + lr) * 1024 + h * 64 + lg * 8;
  const bf16x8 bq0 = ldbf8(qp);
  const bf16x8 bq1 = ldbf8(qp + 32);

  const unsigned short* KfB = Kf + (size_t)bh * 65536;
  const unsigned short* VfB = Vf + (size_t)bh * 65536;
  const unsigned short* mfp = Mf + (size_t)((b * 64 + qb * 4 + w) * 64) * 256 + wl * 4;

  f32x4 O[4];
  float l_ = 0.f;
#pragma unroll
  for (int dt = 0; dt < 4; ++dt) O[dt] = f32x4{0.f, 0.f, 0.f, 0.f};
  unsigned short* sp = &sP[w][0];

  auto stage = [&](int kc, int buf) {
    const unsigned short* srcs[4] = {KfB + kc * 2048, KfB + 32768 + kc * 2048,
                                     VfB + kc * 4096, VfB + kc * 4096 + 2048};
#pragma unroll
    for (int r = 0; r < 4; ++r) {
      const char* g = (const char*)(srcs[r] + (size_t)t * 8);
      char* l = (char*)&S[buf][r * 2048 + w * 512];
      glds16(g, l);
    }
  };

  stage(0, 0);
  __syncthreads();

  for (int kc = 0; kc < 16; ++kc) {
    const int buf = kc & 1;
    if (kc < 15) stage(kc + 1, buf ^ 1);

    us4 mk[4];
#pragma unroll
    for (int t4 = 0; t4 < 4; ++t4)
      mk[t4] = *reinterpret_cast<const us4*>(mfp + (size_t)(kc * 4 + t4) * 256);

    bf16x8 ak[4][2];
#pragma unroll
    for (int t4 = 0; t4 < 4; ++t4) {
      ak[t4][0] = ldbf8(&S[buf][t4 * 512 + wl * 8]);
      ak[t4][1] = ldbf8(&S[buf][2048 + t4 * 512 + wl * 8]);
    }

    f32x4 sc[4];
    __builtin_amdgcn_s_setprio(1);
#pragma unroll
    for (int t4 = 0; t4 < 4; ++t4) {
      f32x4 a;
#pragma unroll
      for (int r = 0; r < 4; ++r) a[r] = b2f(mk[t4][r]);
      a = MFMA(ak[t4][0], bq0, a);
      a = MFMA(ak[t4][1], bq1, a);
      sc[t4] = a;
    }
    __builtin_amdgcn_s_setprio(0);

    float ps = 0.f;
#pragma unroll
    for (int t4 = 0; t4 < 4; ++t4) {
      const float e0 = EXP2(sc[t4][0]), e1 = EXP2(sc[t4][1]);
      const float e2 = EXP2(sc[t4][2]), e3 = EXP2(sc[t4][3]);
      ps += (e0 + e1) + (e2 + e3);
      uint2 pw;
      pw.x = cvtpk(e0, e1);
      pw.y = cvtpk(e2, e3);
      *reinterpret_cast<uint2*>((char*)sp + lr * 128 + ((t4 * 32 + lg * 8) ^ swz)) = pw;
    }
    ps += __shfl_xor(ps, 16);
    ps += __shfl_xor(ps, 32);
    l_ += ps;

    __builtin_amdgcn_s_setprio(1);
#pragma unroll
    for (int ks = 0; ks < 2; ++ks) {
      bf16x8 ap =
          ldbf8((const unsigned short*)((char*)sp + lr * 128 + ((ks * 64 + lg * 16) ^ swz)));
#pragma unroll
      for (int dt = 0; dt < 4; ++dt) {
        bf16x8 bv = ldbf8(&S[buf][4096 + ks * 2048 + dt * 512 + wl * 8]);
        O[dt] = MFMA(ap, bv, O[dt]);
      }
    }
    __builtin_amdgcn_s_setprio(0);

    __syncthreads();
  }

  float linv[4];
#pragma unroll
  for (int r = 0; r < 4; ++r) linv[r] = 1.0f / __shfl(l_, lg * 4 + r);
#pragma unroll
  for (int dt = 0; dt < 4; ++dt)
#pragma unroll
    for (int r = 0; r < 4; ++r)
      ctx[(size_t)(b * 1024 + q0 + lg * 4 + r) * 1024 + h * 64 + dt * 16 + lr] =
          f2b(O[dt][r] * linv[r]);
}

extern "C" void kernel_launch(void* const* d_in, const int* in_sizes, int n_in,
                              void* d_out, int out_size, void* d_ws, size_t ws_size,
                              hipStream_t stream) {
  const float* query = (const float*)d_in[0];
  const float* key   = (const float*)d_in[1];
  const float* value = (const float*)d_in[2];
  const int*   mask  = (const int*)d_in[3];
  const float* wq = (const float*)d_in[4];
  const float* bq = (const float*)d_in[5];
  const float* wk = (const float*)d_in[6];
  const float* bk = (const float*)d_in[7];
  const float* wv = (const float*)d_in[8];
  const float* bv = (const float*)d_in[9];
  const float* wo = (const float*)d_in[10];
  const float* bo = (const float*)d_in[11];
  float* out = (float*)d_out;

  // ws [0..32MB): Qb, Kf, Vf, ctx (bf16, 8MB each). ctx slot doubles as Abfk
  // during the projection. d_out: Abfq [0..8M) then Mf overlays it; Wb [8..14M).
  // Abfv at ws+32MB only if ws_size >= 40MB. wo(bf16) -> Vf slot after attn.
  const size_t SZ = (size_t)4096 * 1024;
  unsigned short* Qb   = (unsigned short*)d_ws;
  unsigned short* Kf   = Qb + SZ;
  unsigned short* Vf   = Kf + SZ;
  unsigned short* ctx  = Vf + SZ;
  unsigned short* Abfq = (unsigned short*)d_out;
  unsigned short* Wb   = Abfq + SZ;
  unsigned short* Mf   = (unsigned short*)d_out;  // after projection
  unsigned short* Abfk = ctx;                     // before attn
  const bool big = ws_size >= (size_t)40 * 1024 * 1024;
  unsigned short* Abfv = big ? (ctx + SZ) : nullptr;  // ws+32MB
  unsigned short* Wob  = Vf;                          // after attn

  const float qscale = 0.125f * 1.4426950408889634f;  // 1/sqrt(64) * log2(e)
  dim3 blk(256);
  prep<<<big ? 7680 : 5632, blk, 0, stream>>>(query, key, value, wq, wk, wv,
                                              Abfq, Abfk, Abfv, Wb);
  gemm_proj<<<dim3(32, 8, 3), dim3(512), 0, stream>>>(Abfq, Abfk, Abfv, value, Wb,
                                                      bq, bk, bv, Qb, Kf, Vf, qscale);
  maskcvt<<<4096, blk, 0, stream>>>(mask, Mf);
  attn_v7<<<dim3(64, 16), blk, 0, stream>>>(Qb, Kf, Vf, Mf, ctx);
  cvt_w<<<512, blk, 0, stream>>>(wo, Wob);
  gemm_out<<<dim3(32, 16), blk, 0, stream>>>(ctx, Wob, bo, out);
}

// Round 19
// 114.896 us; speedup vs baseline: 1.0725x; 1.0138x over previous
//
#include <hip/hip_runtime.h>
#include <hip/hip_bf16.h>

// MHA forward: B=4, S=1024, D=1024, H=16, DK=64.
// v19: attn_v10 = 32 q-rows/wave (dual-qs; halves per-CU LDS-read redundancy);
// gemm_out widened to 512 threads (R16 recipe). gemm_proj = v18 (conflict-free
// interleaved LDS). prep/maskcvt/cvt_w unchanged.

typedef __bf16 bf16x8 __attribute__((ext_vector_type(8)));
typedef float f32x4 __attribute__((ext_vector_type(4)));
typedef unsigned short us8 __attribute__((ext_vector_type(8)));
typedef unsigned short us4 __attribute__((ext_vector_type(4)));

#define MFMA(a, b, c) __builtin_amdgcn_mfma_f32_16x16x32_bf16(a, b, c, 0, 0, 0)
#define EXP2(x) __builtin_amdgcn_exp2f(x)

__device__ __forceinline__ unsigned short f2b(float f) {
  return __builtin_bit_cast(unsigned short, __float2bfloat16(f));
}
__device__ __forceinline__ float b2f(unsigned short u) {
  return __builtin_bit_cast(float, (unsigned)u << 16);
}
__device__ __forceinline__ unsigned cvtpk(float lo, float hi) {
  unsigned r;
  asm("v_cvt_pk_bf16_f32 %0, %1, %2" : "=v"(r) : "v"(lo), "v"(hi));
  return r;
}
__device__ __forceinline__ bf16x8 ldbf8(const unsigned short* p) {
  return __builtin_bit_cast(bf16x8, *reinterpret_cast<const us8*>(p));
}
__device__ __forceinline__ us8 cvt8(float4 a, float4 b) {
  us8 o;
  o[0] = f2b(a.x); o[1] = f2b(a.y); o[2] = f2b(a.z); o[3] = f2b(a.w);
  o[4] = f2b(b.x); o[5] = f2b(b.y); o[6] = f2b(b.z); o[7] = f2b(b.w);
  return o;
}
__device__ __forceinline__ void glds16(const void* g, void* l) {
  __builtin_amdgcn_global_load_lds(
      (const __attribute__((address_space(1))) unsigned int*)g,
      (__attribute__((address_space(3))) unsigned int*)l, 16, 0, 0);
}

// prep: bid [0,1536): wq/wk/wv f32->bf16 -> Wb (3 x 1M elems, row-major).
//       bid [1536,3584): query -> Abfq; [3584,5632): key -> Abfk;
//       bid [5632,7680): value -> Abfv (launched only when ws is big enough).
__global__ __launch_bounds__(256)
void prep(const float* __restrict__ query, const float* __restrict__ key,
          const float* __restrict__ value, const float* __restrict__ wq,
          const float* __restrict__ wk, const float* __restrict__ wv,
          unsigned short* __restrict__ Abfq, unsigned short* __restrict__ Abfk,
          unsigned short* __restrict__ Abfv, unsigned short* __restrict__ Wb) {
  const int bid = blockIdx.x, tid = threadIdx.x;
  const float* src;
  unsigned short* dst;
  size_t off;
  if (bid < 1536) {
    const int widx = bid >> 9;
    src = (widx == 0) ? wq : (widx == 1) ? wk : wv;
    dst = Wb + (size_t)widx * 1048576;
    off = (size_t)(bid & 511) * 2048 + tid * 8;
  } else if (bid < 3584) {
    src = query; dst = Abfq; off = (size_t)(bid - 1536) * 2048 + tid * 8;
  } else if (bid < 5632) {
    src = key; dst = Abfk; off = (size_t)(bid - 3584) * 2048 + tid * 8;
  } else {
    src = value; dst = Abfv; off = (size_t)(bid - 5632) * 2048 + tid * 8;
  }
  const float4* p = reinterpret_cast<const float4*>(src + off);
  *reinterpret_cast<us8*>(dst + off) = cvt8(p[0], p[1]);
}

// mask[b][q][k] -> Mf in swapped QK^T C-frag order (C[k][q], q=lane&15).
// Fixed-offset softmax: unmasked = bf16(-24), masked = bf16(-1.44e9) = 0xCEAC.
__global__ __launch_bounds__(256)
void maskcvt(const int* __restrict__ mask, unsigned short* __restrict__ Mf) {
  const int idx = blockIdx.x * 256 + threadIdx.x;
  const int wl = idx & 63, tile = idx >> 6;
  const int kt = tile & 63, qt = (tile >> 6) & 63, b = tile >> 12;
  const int lr = wl & 15, lg = wl >> 4;
  const int4 mv = *reinterpret_cast<const int4*>(
      mask + (size_t)(b * 1024 + qt * 16 + lr) * 1024 + kt * 16 + lg * 4);
  us4 o;
  o[0] = mv.x ? 0xCEACu : 0xC1C0u;
  o[1] = mv.y ? 0xCEACu : 0xC1C0u;
  o[2] = mv.z ? 0xCEACu : 0xC1C0u;
  o[3] = mv.w ? 0xCEACu : 0xC1C0u;
  *reinterpret_cast<us4*>(Mf + (size_t)idx * 4) = o;
}

// single f32->bf16 1M convert (wo, after attn frees Vf slot)
__global__ __launch_bounds__(256)
void cvt_w(const float* __restrict__ src, unsigned short* __restrict__ dst) {
  const size_t off = (size_t)blockIdx.x * 2048 + threadIdx.x * 8;
  const float4* p = reinterpret_cast<const float4*>(src + off);
  *reinterpret_cast<us8*>(dst + off) = cvt8(p[0], p[1]);
}

// Projection GEMM v18 (unchanged): BM=128, BN=128, BK=32; 512 threads = 8
// waves (2x4); dbuf 32KB LDS; row-pair-interleaved conflict-free layout.
__global__ __launch_bounds__(512, 6)
void gemm_proj(const unsigned short* __restrict__ Aq,
               const unsigned short* __restrict__ Ak,
               const unsigned short* __restrict__ Av_bf,
               const float* __restrict__ Av_f32,
               const unsigned short* __restrict__ Wb,
               const float* __restrict__ bq, const float* __restrict__ bk,
               const float* __restrict__ bv, unsigned short* __restrict__ Qb,
               unsigned short* __restrict__ Kf, unsigned short* __restrict__ Vf,
               float qscale) {
  constexpr int K = 1024, N = 1024;
  __shared__ __align__(16) unsigned short As[2][128 * 32];
  __shared__ __align__(16) unsigned short Bs[2][128 * 32];
  const int lid = blockIdx.x + (blockIdx.y << 5) + (blockIdx.z << 8);
  const int xcd = lid & 7, slot = lid >> 3;
  const int chunk = ((slot >> 3) << 3) + xcd;
  const int z = chunk >> 5;
  const int bm = (chunk & 31) * 128;
  const int bn = (slot & 7) * 128;

  const unsigned short* Abf = (z == 0) ? Aq : (z == 1) ? Ak : Av_bf;
  const bool f32path = (z == 2) && (Av_bf == nullptr);
  const unsigned short* Bw = Wb + (size_t)z * 1048576;
  const float* bias = (z == 0) ? bq : (z == 1) ? bk : bv;
  const int t = threadIdx.x;
  const int w = t >> 6, lane = t & 63, lr = lane & 15, lg = lane >> 4;
  const int wr = w >> 2, wc = w & 3;

  const int sline = t >> 3;
  const int su = (t & 7) ^ (sline & 7);
  const int srow = sline * 2 + (su >> 2);
  const int scol = (su & 3) * 8;

  f32x4 acc[4][2];
#pragma unroll
  for (int m = 0; m < 4; ++m)
#pragma unroll
    for (int n = 0; n < 2; ++n) acc[m][n] = f32x4{0.f, 0.f, 0.f, 0.f};

  auto stageA = [&](int k0, int buf) {
    const char* g = (const char*)(Abf + (size_t)(bm + srow) * 1024 + k0 + scol);
    char* l = (char*)&As[buf][0] + (w * 64) * 16;
    glds16(g, l);
  };
  auto stageB = [&](int k0, int buf) {
    const char* g = (const char*)(Bw + (size_t)(bn + srow) * 1024 + k0 + scol);
    char* l = (char*)&Bs[buf][0] + (w * 64) * 16;
    glds16(g, l);
  };
#define STA8(buf, v)                                                           \
  { *reinterpret_cast<us8*>((char*)&As[buf][0] + t * 16) = (v); }
#define RDOFF(row) (((row) >> 1) * 128 +                                       \
                    (((lg | (((row) & 1) << 2)) ^ (((row) >> 1) & 7)) * 16))

  if (f32path) {
    const float4* p =
        reinterpret_cast<const float4*>(Av_f32 + (size_t)(bm + srow) * K + scol);
    STA8(0, cvt8(p[0], p[1]));
  } else {
    stageA(0, 0);
  }
  stageB(0, 0);
  __syncthreads();

  for (int c = 0; c < 32; ++c) {
    const int buf = c & 1;
    float4 fa[2];
    if (c < 31) {
      const int k1 = (c + 1) * 32;
      if (f32path) {
        const float4* p = reinterpret_cast<const float4*>(
            Av_f32 + (size_t)(bm + srow) * K + k1 + scol);
        fa[0] = p[0];
        fa[1] = p[1];
      } else {
        stageA(k1, buf ^ 1);
      }
      stageB(k1, buf ^ 1);
    }
    {
      bf16x8 af[4], bfr[2];
#pragma unroll
      for (int m = 0; m < 4; ++m) {
        const int row = wr * 64 + m * 16 + lr;
        af[m] = ldbf8((const unsigned short*)((char*)&As[buf][0] + RDOFF(row)));
      }
#pragma unroll
      for (int n = 0; n < 2; ++n) {
        const int row = wc * 32 + n * 16 + lr;
        bfr[n] = ldbf8((const unsigned short*)((char*)&Bs[buf][0] + RDOFF(row)));
      }
#pragma unroll
      for (int m = 0; m < 4; ++m)
#pragma unroll
        for (int n = 0; n < 2; ++n) acc[m][n] = MFMA(af[m], bfr[n], acc[m][n]);
    }
    if (c < 31 && f32path) {
      STA8(buf ^ 1, cvt8(fa[0], fa[1]));
    }
    __syncthreads();
  }
#undef STA8
#undef RDOFF

#pragma unroll
  for (int m = 0; m < 4; ++m) {
    const int mr = bm + wr * 64 + m * 16 + lg * 4;
#pragma unroll
    for (int nt = 0; nt < 2; ++nt) {
      const int n = bn + wc * 32 + nt * 16 + lr;
      const float bb = bias[n];
      if (z == 0) {
#pragma unroll
        for (int r = 0; r < 4; ++r)
          Qb[(size_t)(mr + r) * N + n] = f2b((acc[m][nt][r] + bb) * qscale);
      } else if (z == 1) {
        // Kf: K[bh][s][d] -> bh*65536 + (d>>5)*32768 + (s>>4)*512
        //     + ((s&15)|(((d>>3)&3)<<4))*8 + (d&7)
        const int b2 = mr >> 10, s0 = mr & 1023, hh = n >> 6, dd = n & 63;
        const size_t base = (size_t)(b2 * 16 + hh) * 65536 + (size_t)(dd >> 5) * 32768 +
                            (size_t)(s0 >> 4) * 512 +
                            (size_t)((s0 & 15) | (((dd >> 3) & 3) << 4)) * 8 + (dd & 7);
#pragma unroll
        for (int r = 0; r < 4; ++r) Kf[base + r * 8] = f2b(acc[m][nt][r] + bb);
      } else {
        // Vf: V[bh][s][d] -> bh*65536 + (s>>5)*2048 + (d>>4)*512
        //     + ((d&15)|(((s>>3)&3)<<4))*8 + (s&7)
        const int b2 = mr >> 10, s0 = mr & 1023, hh = n >> 6, dd = n & 63;
        const size_t base = (size_t)(b2 * 16 + hh) * 65536 + (size_t)(s0 >> 5) * 2048 +
                            (size_t)(dd >> 4) * 512 +
                            (size_t)((dd & 15) | (((s0 >> 3) & 3) << 4)) * 8 + (s0 & 7);
        us4 pk;
#pragma unroll
        for (int r = 0; r < 4; ++r) pk[r] = f2b(acc[m][nt][r] + bb);
        *reinterpret_cast<us4*>(&Vf[base]) = pk;
      }
    }
  }
}

// Output projection v19: BM=128, BN=64, BK=64; 512 threads = 8 waves (4x2),
// wave tile 32x32 -> 16 waves/CU (was 8). Same dbuf glds staging + swizzle.
__global__ __launch_bounds__(512, 4)
void gemm_out(const unsigned short* __restrict__ A, const unsigned short* __restrict__ Bw,
              const float* __restrict__ bias, float* __restrict__ Out) {
  constexpr int K = 1024, N = 1024;
  __shared__ __align__(16) unsigned short As[2][128 * 64];
  __shared__ __align__(16) unsigned short Bs[2][64 * 64];
  const int lid = blockIdx.x + (blockIdx.y << 5);
  const int xcd = lid & 7, slot = lid >> 3;
  const int chunk = ((slot >> 5) << 3) + xcd;
  const int pos = slot & 31;
  const int bm = ((chunk << 1) + (pos >> 4)) * 128;
  const int bn = (pos & 15) * 64;
  const int t = threadIdx.x;
  const int w = t >> 6, lane = t & 63, lr = lane & 15, lg = lane >> 4;
  const int wr = w >> 1, wc = w & 1;  // 4x2 wave grid
  const int swzc = (lr & 7) << 4;

  f32x4 acc[2][2];
#pragma unroll
  for (int m = 0; m < 2; ++m)
#pragma unroll
    for (int n = 0; n < 2; ++n) acc[m][n] = f32x4{0.f, 0.f, 0.f, 0.f};

  auto stageA = [&](int k0, int buf) {
#pragma unroll
    for (int it = 0; it < 2; ++it) {
      const int s = it * 512 + t, row = s >> 3, cb = (s & 7) * 16;
      const char* g = (const char*)A + ((size_t)(bm + row) * 1024 + k0) * 2 +
                      (cb ^ ((row & 7) << 4));
      char* l = (char*)&As[buf][0] + (it * 512 + w * 64) * 16;
      glds16(g, l);
    }
  };
  auto stageB = [&](int k0, int buf) {
    const int s = t, row = s >> 3, cb = (s & 7) * 16;
    const char* g = (const char*)Bw + ((size_t)(bn + row) * 1024 + k0) * 2 +
                    (cb ^ ((row & 7) << 4));
    char* l = (char*)&Bs[buf][0] + (w * 64) * 16;
    glds16(g, l);
  };

  stageA(0, 0);
  stageB(0, 0);
  __syncthreads();

  for (int c = 0; c < 16; ++c) {
    const int buf = c & 1;
    if (c < 15) {
      const int k1 = (c + 1) * 64;
      stageA(k1, buf ^ 1);
      stageB(k1, buf ^ 1);
    }
#pragma unroll
    for (int h2 = 0; h2 < 2; ++h2) {
      bf16x8 af[2], bfr[2];
#pragma unroll
      for (int m = 0; m < 2; ++m) {
        const int row = wr * 32 + m * 16 + lr;
        af[m] = ldbf8((const unsigned short*)((char*)&As[buf][0] + row * 128 +
                                              ((h2 * 64 + lg * 16) ^ swzc)));
      }
#pragma unroll
      for (int n = 0; n < 2; ++n) {
        const int row = wc * 32 + n * 16 + lr;
        bfr[n] = ldbf8((const unsigned short*)((char*)&Bs[buf][0] + row * 128 +
                                               ((h2 * 64 + lg * 16) ^ swzc)));
      }
#pragma unroll
      for (int m = 0; m < 2; ++m)
#pragma unroll
        for (int n = 0; n < 2; ++n) acc[m][n] = MFMA(af[m], bfr[n], acc[m][n]);
    }
    __syncthreads();
  }

#pragma unroll
  for (int m = 0; m < 2; ++m) {
    const int mr = bm + wr * 32 + m * 16 + lg * 4;
#pragma unroll
    for (int nt = 0; nt < 2; ++nt) {
      const int n = bn + wc * 32 + nt * 16 + lr;
      const float bb = bias[n];
#pragma unroll
      for (int r = 0; r < 4; ++r) Out[(size_t)(mr + r) * N + n] = acc[m][nt][r] + bb;
    }
  }
}

// Flash attention v10: 32 q-rows per wave (2 sub-tiles) — halves per-CU LDS
// read redundancy. WG-shared K/V glds staging (dbuf), fixed-offset softmax via
// Mf, cvt_pk P-pack, setprio. Swapped QK^T. grid (64 bh, 8 qb) = 512 WGs.
__global__ __launch_bounds__(256)
void attn_v10(const unsigned short* __restrict__ Qb,
              const unsigned short* __restrict__ Kf,
              const unsigned short* __restrict__ Vf,
              const unsigned short* __restrict__ Mf,
              unsigned short* __restrict__ ctx) {
  __shared__ __align__(16) unsigned short S[2][8192];     // 32 KB
  __shared__ __align__(16) unsigned short sP[4][2][1024]; // 16 KB
  const int lid = blockIdx.x + (blockIdx.y << 6);
  const int xcd = lid & 7, slot = lid >> 3;               // [0,64)
  const int bh = ((slot >> 3) << 3) + xcd;                // [0,64)
  const int qb = slot & 7;                                // [0,8)
  const int b = bh >> 4, h = bh & 15;
  const int t = threadIdx.x, w = t >> 6, wl = t & 63, lr = wl & 15, lg = wl >> 4;
  const int q0 = qb * 128 + w * 32;
  const int swz = (lr & 7) << 4;

  bf16x8 bq[2][2];
#pragma unroll
  for (int qs = 0; qs < 2; ++qs) {
    const unsigned short* qp =
        Qb + (size_t)(b * 1024 + q0 + qs * 16 + lr) * 1024 + h * 64 + lg * 8;
    bq[qs][0] = ldbf8(qp);
    bq[qs][1] = ldbf8(qp + 32);
  }

  const unsigned short* KfB = Kf + (size_t)bh * 65536;
  const unsigned short* VfB = Vf + (size_t)bh * 65536;
  const unsigned short* mfp[2];
#pragma unroll
  for (int qs = 0; qs < 2; ++qs)
    mfp[qs] = Mf + (size_t)((b * 64 + qb * 8 + w * 2 + qs) * 64) * 256 + wl * 4;

  f32x4 O[2][4];
  float l_[2] = {0.f, 0.f};
#pragma unroll
  for (int qs = 0; qs < 2; ++qs)
#pragma unroll
    for (int dt = 0; dt < 4; ++dt) O[qs][dt] = f32x4{0.f, 0.f, 0.f, 0.f};
  unsigned short* sp0 = &sP[w][0][0];
  unsigned short* sp1 = &sP[w][1][0];

  auto stage = [&](int kc, int buf) {
    const unsigned short* srcs[4] = {KfB + kc * 2048, KfB + 32768 + kc * 2048,
                                     VfB + kc * 4096, VfB + kc * 4096 + 2048};
#pragma unroll
    for (int r = 0; r < 4; ++r) {
      const char* g = (const char*)(srcs[r] + (size_t)t * 8);
      char* l = (char*)&S[buf][r * 2048 + w * 512];
      glds16(g, l);
    }
  };

  stage(0, 0);
  __syncthreads();

  for (int kc = 0; kc < 16; ++kc) {
    const int buf = kc & 1;
    if (kc < 15) stage(kc + 1, buf ^ 1);

    us4 mk[2][4];
#pragma unroll
    for (int qs = 0; qs < 2; ++qs)
#pragma unroll
      for (int t4 = 0; t4 < 4; ++t4)
        mk[qs][t4] = *reinterpret_cast<const us4*>(mfp[qs] + (size_t)(kc * 4 + t4) * 256);

    bf16x8 ak[4][2];
#pragma unroll
    for (int t4 = 0; t4 < 4; ++t4) {
      ak[t4][0] = ldbf8(&S[buf][t4 * 512 + wl * 8]);
      ak[t4][1] = ldbf8(&S[buf][2048 + t4 * 512 + wl * 8]);
    }

    // QK^T both q sub-tiles (K frags reused)
    f32x4 sc[2][4];
    __builtin_amdgcn_s_setprio(1);
#pragma unroll
    for (int qs = 0; qs < 2; ++qs)
#pragma unroll
      for (int t4 = 0; t4 < 4; ++t4) {
        f32x4 a;
#pragma unroll
        for (int r = 0; r < 4; ++r) a[r] = b2f(mk[qs][t4][r]);
        a = MFMA(ak[t4][0], bq[qs][0], a);
        a = MFMA(ak[t4][1], bq[qs][1], a);
        sc[qs][t4] = a;
      }
    __builtin_amdgcn_s_setprio(0);

    // fixed-offset softmax per sub-tile
#pragma unroll
    for (int qs = 0; qs < 2; ++qs) {
      unsigned short* sp = qs ? sp1 : sp0;
      float ps = 0.f;
#pragma unroll
      for (int t4 = 0; t4 < 4; ++t4) {
        const float e0 = EXP2(sc[qs][t4][0]), e1 = EXP2(sc[qs][t4][1]);
        const float e2 = EXP2(sc[qs][t4][2]), e3 = EXP2(sc[qs][t4][3]);
        ps += (e0 + e1) + (e2 + e3);
        uint2 pw;
        pw.x = cvtpk(e0, e1);
        pw.y = cvtpk(e2, e3);
        *reinterpret_cast<uint2*>((char*)sp + lr * 128 + ((t4 * 32 + lg * 8) ^ swz)) = pw;
      }
      ps += __shfl_xor(ps, 16);
      ps += __shfl_xor(ps, 32);
      l_[qs] += ps;
    }

    // PV: V frags read once, used by both sub-tiles
    __builtin_amdgcn_s_setprio(1);
#pragma unroll
    for (int ks = 0; ks < 2; ++ks) {
      const int off = lr * 128 + ((ks * 64 + lg * 16) ^ swz);
      bf16x8 apA = ldbf8((const unsigned short*)((char*)sp0 + off));
      bf16x8 apB = ldbf8((const unsigned short*)((char*)sp1 + off));
#pragma unroll
      for (int dt = 0; dt < 4; ++dt) {
        bf16x8 bv = ldbf8(&S[buf][4096 + ks * 2048 + dt * 512 + wl * 8]);
        O[0][dt] = MFMA(apA, bv, O[0][dt]);
        O[1][dt] = MFMA(apB, bv, O[1][dt]);
      }
    }
    __builtin_amdgcn_s_setprio(0);

    __syncthreads();
  }

#pragma unroll
  for (int qs = 0; qs < 2; ++qs) {
    float linv[4];
#pragma unroll
    for (int r = 0; r < 4; ++r) linv[r] = 1.0f / __shfl(l_[qs], lg * 4 + r);
#pragma unroll
    for (int dt = 0; dt < 4; ++dt)
#pragma unroll
      for (int r = 0; r < 4; ++r)
        ctx[(size_t)(b * 1024 + q0 + qs * 16 + lg * 4 + r) * 1024 + h * 64 + dt * 16 + lr] =
            f2b(O[qs][dt][r] * linv[r]);
  }
}

extern "C" void kernel_launch(void* const* d_in, const int* in_sizes, int n_in,
                              void* d_out, int out_size, void* d_ws, size_t ws_size,
                              hipStream_t stream) {
  const float* query = (const float*)d_in[0];
  const float* key   = (const float*)d_in[1];
  const float* value = (const float*)d_in[2];
  const int*   mask  = (const int*)d_in[3];
  const float* wq = (const float*)d_in[4];
  const float* bq = (const float*)d_in[5];
  const float* wk = (const float*)d_in[6];
  const float* bk = (const float*)d_in[7];
  const float* wv = (const float*)d_in[8];
  const float* bv = (const float*)d_in[9];
  const float* wo = (const float*)d_in[10];
  const float* bo = (const float*)d_in[11];
  float* out = (float*)d_out;

  // ws [0..32MB): Qb, Kf, Vf, ctx (bf16, 8MB each). ctx slot doubles as Abfk
  // during the projection. d_out: Abfq [0..8M) then Mf overlays it; Wb [8..14M).
  // Abfv at ws+32MB only if ws_size >= 40MB. wo(bf16) -> Vf slot after attn.
  const size_t SZ = (size_t)4096 * 1024;
  unsigned short* Qb   = (unsigned short*)d_ws;
  unsigned short* Kf   = Qb + SZ;
  unsigned short* Vf   = Kf + SZ;
  unsigned short* ctx  = Vf + SZ;
  unsigned short* Abfq = (unsigned short*)d_out;
  unsigned short* Wb   = Abfq + SZ;
  unsigned short* Mf   = (unsigned short*)d_out;  // after projection
  unsigned short* Abfk = ctx;                     // before attn
  const bool big = ws_size >= (size_t)40 * 1024 * 1024;
  unsigned short* Abfv = big ? (ctx + SZ) : nullptr;  // ws+32MB
  unsigned short* Wob  = Vf;                          // after attn

  const float qscale = 0.125f * 1.4426950408889634f;  // 1/sqrt(64) * log2(e)
  dim3 blk(256);
  prep<<<big ? 7680 : 5632, blk, 0, stream>>>(query, key, value, wq, wk, wv,
                                              Abfq, Abfk, Abfv, Wb);
  gemm_proj<<<dim3(32, 8, 3), dim3(512), 0, stream>>>(Abfq, Abfk, Abfv, value, Wb,
                                                      bq, bk, bv, Qb, Kf, Vf, qscale);
  maskcvt<<<4096, blk, 0, stream>>>(mask, Mf);
  attn_v10<<<dim3(64, 8), blk, 0, stream>>>(Qb, Kf, Vf, Mf, ctx);
  cvt_w<<<512, blk, 0, stream>>>(wo, Wob);
  gemm_out<<<dim3(32, 16), dim3(512), 0, stream>>>(ctx, Wob, bo, out);
}